// Round 3
// baseline (888.815 us; speedup 1.0000x reference)
//
#include <hip/hip_runtime.h>
#include <stdint.h>
#include <math.h>

#define NEG 0.2f
#define TINYF 1.1754943508222875e-38f

// ---------------- Threefry-2x32-20 (matches JAX) ----------------
__host__ __device__ inline void threefry2x32(uint32_t k0, uint32_t k1,
                                             uint32_t x0, uint32_t x1,
                                             uint32_t* o0, uint32_t* o1) {
  uint32_t ks0 = k0, ks1 = k1, ks2 = k0 ^ k1 ^ 0x1BD11BDAu;
  x0 += ks0; x1 += ks1;
#define RR(r) { x0 += x1; x1 = (x1 << (r)) | (x1 >> (32 - (r))); x1 ^= x0; }
  RR(13) RR(15) RR(26) RR(6)
  x0 += ks1; x1 += ks2 + 1u;
  RR(17) RR(29) RR(16) RR(24)
  x0 += ks2; x1 += ks0 + 2u;
  RR(13) RR(15) RR(26) RR(6)
  x0 += ks0; x1 += ks1 + 3u;
  RR(17) RR(29) RR(16) RR(24)
  x0 += ks1; x1 += ks2 + 4u;
  RR(13) RR(15) RR(26) RR(6)
  x0 += ks2; x1 += ks0 + 5u;
#undef RR
  *o0 = x0; *o1 = x1;
}

// jax_threefry_partitionable=True random_bits, bit_width=32:
//   counts = iota(uint64, n); (b1,b2) = TF(key, (count>>32, count&0xffffffff))
//   bits[i] = b1 ^ b2      <-- xor narrowing, NOT truncation
__device__ inline float gumbel_part(uint32_t ka, uint32_t kb, uint32_t i) {
  uint32_t o0, o1;
  threefry2x32(ka, kb, 0u, i, &o0, &o1);
  uint32_t bits = o0 ^ o1;
  float f = __uint_as_float((bits >> 9) | 0x3f800000u) - 1.0f;
  float u = fmaxf(TINYF, f + TINYF);
  return -logf(-logf(u));
}

// ---------------- CSR build ----------------
__global__ void count_kernel(const int* __restrict__ ei, int E, int* __restrict__ counts) {
  int e = blockIdx.x * blockDim.x + threadIdx.x;
  if (e < E) atomicAdd(&counts[ei[E + e]], 1);
}

__global__ __launch_bounds__(1024) void scan_kernel(const int* __restrict__ counts,
    int* __restrict__ row_start, int* __restrict__ cursor, int N, int E) {
  __shared__ int a[1024], b[1024];
  __shared__ int base_s;
  int tid = threadIdx.x;
  if (tid == 0) base_s = 0;
  __syncthreads();
  for (int chunk = 0; chunk < N; chunk += 1024) {
    int i = chunk + tid;
    int v = (i < N) ? counts[i] : 0;
    a[tid] = v;
    __syncthreads();
    int* srcp = a; int* dstp = b;
    for (int off = 1; off < 1024; off <<= 1) {
      int val = srcp[tid];
      if (tid >= off) val += srcp[tid - off];
      dstp[tid] = val;
      __syncthreads();
      int* t = srcp; srcp = dstp; dstp = t;
    }
    int incl = srcp[tid];
    int excl = incl - v;
    int base = base_s;
    if (i < N) { row_start[i] = base + excl; cursor[i] = base + excl; }
    __syncthreads();
    if (tid == 1023) base_s = base + incl;
    __syncthreads();
  }
  if (tid == 0) row_start[N] = base_s;
}

__global__ void scatter_kernel(const int* __restrict__ ei, int E,
                               int* __restrict__ cursor, int* __restrict__ eid) {
  int e = blockIdx.x * blockDim.x + threadIdx.x;
  if (e < E) {
    int d = ei[E + e];
    int p = atomicAdd(&cursor[d], 1);
    eid[p] = e;
  }
}

// ---------------- h = X @ W (128x128) + b ----------------
__global__ __launch_bounds__(256) void gemm128_kernel(const float* __restrict__ X,
    const float* __restrict__ W, const float* __restrict__ bias,
    float* __restrict__ out, int M) {
  __shared__ float xs[128][33];  // xs[k][r], padded
  int row0 = blockIdx.x * 32;
  int tid = threadIdx.x;
  for (int idx = tid; idx < 32 * 128; idx += 256) {
    int r = idx >> 7;
    int k = idx & 127;
    int row = row0 + r;
    xs[k][r] = (row < M) ? X[(size_t)row * 128 + k] : 0.0f;
  }
  __syncthreads();
  int tc = tid & 31, tr = tid >> 5;
  int c0 = tc * 4, r0 = tr * 4;
  float acc[4][4] = {};
#pragma unroll 4
  for (int k = 0; k < 128; k++) {
    float4 w = *(const float4*)&W[k * 128 + c0];
    float x0 = xs[k][r0], x1 = xs[k][r0 + 1], x2 = xs[k][r0 + 2], x3 = xs[k][r0 + 3];
    acc[0][0] += x0 * w.x; acc[0][1] += x0 * w.y; acc[0][2] += x0 * w.z; acc[0][3] += x0 * w.w;
    acc[1][0] += x1 * w.x; acc[1][1] += x1 * w.y; acc[1][2] += x1 * w.z; acc[1][3] += x1 * w.w;
    acc[2][0] += x2 * w.x; acc[2][1] += x2 * w.y; acc[2][2] += x2 * w.z; acc[2][3] += x2 * w.w;
    acc[3][0] += x3 * w.x; acc[3][1] += x3 * w.y; acc[3][2] += x3 * w.z; acc[3][3] += x3 * w.w;
  }
  float4 b4 = *(const float4*)&bias[c0];
  for (int r = 0; r < 4; r++) {
    int row = row0 + r0 + r;
    if (row < M) {
      float4 o;
      o.x = acc[r][0] + b4.x; o.y = acc[r][1] + b4.y;
      o.z = acc[r][2] + b4.z; o.w = acc[r][3] + b4.w;
      *(float4*)&out[(size_t)row * 128 + c0] = o;
    }
  }
}

// ---------------- h3 = latent @ Wl3 (128x32) + b ----------------
__global__ __launch_bounds__(256) void gemm32_kernel(const float* __restrict__ X,
    const float* __restrict__ W, const float* __restrict__ bias,
    float* __restrict__ out, int M) {
  int t = blockIdx.x * 256 + threadIdx.x;
  int node = t >> 5, c = t & 31;
  if (node >= M) return;
  const float4* xp = (const float4*)&X[(size_t)node * 128];
  float acc = 0.f;
#pragma unroll
  for (int q = 0; q < 32; q++) {
    float4 x4 = xp[q];
    acc += x4.x * W[(q * 4 + 0) * 32 + c] + x4.y * W[(q * 4 + 1) * 32 + c]
         + x4.z * W[(q * 4 + 2) * 32 + c] + x4.w * W[(q * 4 + 3) * 32 + c];
  }
  out[(size_t)node * 32 + c] = acc + bias[c];
}

// ---------------- h2 = latent @ Wl2 (128x1) + b ----------------
__global__ __launch_bounds__(256) void gemv_kernel(const float* __restrict__ X,
    const float* __restrict__ w, const float* __restrict__ b0,
    float* __restrict__ out, int M) {
  int wv = (blockIdx.x * 256 + threadIdx.x) >> 6;
  int lane = threadIdx.x & 63;
  if (wv >= M) return;
  float2 xv = *(const float2*)&X[(size_t)wv * 128 + lane * 2];
  float2 wvv = *(const float2*)&w[lane * 2];
  float v = xv.x * wvv.x + xv.y * wvv.y;
#pragma unroll
  for (int off = 32; off; off >>= 1) v += __shfl_xor(v, off);
  if (lane == 0) out[wv] = v + b0[0];
}

// ---------------- layer-1 edge scores (wave per edge, 8 edges/wave loop) ----------------
__global__ __launch_bounds__(256) void escore1_kernel(const float* __restrict__ h,
    const int* __restrict__ ei, const float* __restrict__ ea,
    const float* __restrict__ We, const float* __restrict__ att,
    float* __restrict__ s_out, int E) {
  __shared__ float WeS[2048];
  __shared__ float attS[128];
  int tid = threadIdx.x;
  for (int i = tid; i < 2048; i += 256) WeS[i] = We[i];
  if (tid < 128) attS[tid] = att[tid];
  __syncthreads();
  int lane = tid & 63;
  int wv = tid >> 6;
  int l2 = lane * 2;
  float2 attv = *(const float2*)&attS[l2];
  int ebase = (blockIdx.x * 4 + wv) * 8;
  for (int t = 0; t < 8; t++) {
    int e = ebase + t;
    if (e >= E) break;
    int s = ei[e], d = ei[E + e];
    float2 hd = *(const float2*)&h[(size_t)d * 128 + l2];
    float2 hs = *(const float2*)&h[(size_t)s * 128 + l2];
    const float* eap = &ea[(size_t)e * 16];
    float v0 = hd.x + hs.x, v1 = hd.y + hs.y;
#pragma unroll
    for (int k = 0; k < 16; k++) {
      float a = eap[k];
      float2 w2 = *(const float2*)&WeS[k * 128 + l2];
      v0 += a * w2.x; v1 += a * w2.y;
    }
    v0 = v0 >= 0.f ? v0 : NEG * v0;
    v1 = v1 >= 0.f ? v1 : NEG * v1;
    float sc = v0 * attv.x + v1 * attv.y;
#pragma unroll
    for (int off = 32; off; off >>= 1) sc += __shfl_xor(sc, off);
    if (lane == 0) s_out[e] = sc;
  }
}

// ---------------- layer-2 edge scores (thread per edge) ----------------
__global__ void escore2_kernel(const float* __restrict__ h2, const int* __restrict__ ei,
    const float* __restrict__ ea, const float* __restrict__ We,
    const float* __restrict__ att, float* __restrict__ s_out, int E) {
  int e = blockIdx.x * blockDim.x + threadIdx.x;
  if (e >= E) return;
  float v = h2[ei[E + e]] + h2[ei[e]];
  const float4* eap = (const float4*)&ea[(size_t)e * 16];
#pragma unroll
  for (int q = 0; q < 4; q++) {
    float4 a = eap[q];
    v += a.x * We[q * 4 + 0] + a.y * We[q * 4 + 1] + a.z * We[q * 4 + 2] + a.w * We[q * 4 + 3];
  }
  v = v >= 0.f ? v : NEG * v;
  s_out[e] = v * att[0];
}

// ---------------- layer-3 edge scores (half-wave per edge) ----------------
__global__ __launch_bounds__(256) void escore3_kernel(const float* __restrict__ h3,
    const int* __restrict__ ei, const float* __restrict__ ea,
    const float* __restrict__ We, const float* __restrict__ att,
    float* __restrict__ s_out, int E) {
  __shared__ float WeS[512];
  __shared__ float attS[32];
  int tid = threadIdx.x;
  for (int i = tid; i < 512; i += 256) WeS[i] = We[i];
  if (tid < 32) attS[tid] = att[tid];
  __syncthreads();
  int c = tid & 31;
  int hw = tid >> 5;
  float attv = attS[c];
  int ebase = (blockIdx.x * 8 + hw) * 8;
  for (int t = 0; t < 8; t++) {
    int e = ebase + t;
    if (e >= E) break;
    int s = ei[e], d = ei[E + e];
    float v = h3[(size_t)d * 32 + c] + h3[(size_t)s * 32 + c];
    const float* eap = &ea[(size_t)e * 16];
#pragma unroll
    for (int k = 0; k < 16; k++) v += eap[k] * WeS[k * 32 + c];
    v = v >= 0.f ? v : NEG * v;
    v *= attv;
#pragma unroll
    for (int off = 16; off; off >>= 1) v += __shfl_xor(v, off);
    if (c == 0) s_out[e] = v;
  }
}

// ---------------- layer-1 aggregate (wave per node, 128-wide) ----------------
__global__ __launch_bounds__(256) void agg1_kernel(const float* __restrict__ h,
    const int* __restrict__ ei, const float* __restrict__ sc,
    const int* __restrict__ row_start, const int* __restrict__ eid,
    const float* __restrict__ bias, float* __restrict__ out, int N) {
  int wv = (blockIdx.x * 256 + threadIdx.x) >> 6;
  int lane = threadIdx.x & 63;
  if (wv >= N) return;
  int start = row_start[wv];
  int deg = row_start[wv + 1] - start;
  float2 acc = make_float2(0.f, 0.f);
  if (deg > 0) {
    int e_l = 0; float s_l = -INFINITY;
    if (lane < deg) { e_l = eid[start + lane]; s_l = sc[e_l]; }
    float m = s_l;
    for (int j = lane + 64; j < deg; j += 64) m = fmaxf(m, sc[eid[start + j]]);
#pragma unroll
    for (int off = 32; off; off >>= 1) m = fmaxf(m, __shfl_xor(m, off));
    float ds = (lane < deg) ? expf(s_l - m) : 0.f;
    for (int j = lane + 64; j < deg; j += 64) ds += expf(sc[eid[start + j]] - m);
#pragma unroll
    for (int off = 32; off; off >>= 1) ds += __shfl_xor(ds, off);
    float inv = 1.0f / (ds + 1e-16f);
    int dmin = deg < 64 ? deg : 64;
    for (int j = 0; j < dmin; j++) {
      int e = __shfl(e_l, j);
      float w = expf(__shfl(s_l, j) - m) * inv;
      float2 hv = *(const float2*)&h[(size_t)ei[e] * 128 + lane * 2];
      acc.x += w * hv.x; acc.y += w * hv.y;
    }
    for (int j = 64; j < deg; j++) {
      int e = eid[start + j];
      float w = expf(sc[e] - m) * inv;
      float2 hv = *(const float2*)&h[(size_t)ei[e] * 128 + lane * 2];
      acc.x += w * hv.x; acc.y += w * hv.y;
    }
  }
  float2 b2 = *(const float2*)&bias[lane * 2];
  float2 o; o.x = acc.x + b2.x; o.y = acc.y + b2.y;
  *(float2*)&out[(size_t)wv * 128 + lane * 2] = o;
}

// ---------------- layer-2 aggregate (wave per node, scalar) ----------------
__global__ __launch_bounds__(256) void agg2_kernel(const float* __restrict__ h2,
    const int* __restrict__ ei, const float* __restrict__ sc,
    const int* __restrict__ row_start, const int* __restrict__ eid,
    const float* __restrict__ bias2, float* __restrict__ logits, int N) {
  int wv = (blockIdx.x * 256 + threadIdx.x) >> 6;
  int lane = threadIdx.x & 63;
  if (wv >= N) return;
  int start = row_start[wv];
  int deg = row_start[wv + 1] - start;
  float result = 0.f;
  if (deg > 0) {
    float m = -INFINITY;
    for (int j = lane; j < deg; j += 64) m = fmaxf(m, sc[eid[start + j]]);
#pragma unroll
    for (int off = 32; off; off >>= 1) m = fmaxf(m, __shfl_xor(m, off));
    float ds = 0.f, num = 0.f;
    for (int j = lane; j < deg; j += 64) {
      int e = eid[start + j];
      float ex = expf(sc[e] - m);
      ds += ex;
      num += ex * h2[ei[e]];
    }
#pragma unroll
    for (int off = 32; off; off >>= 1) { ds += __shfl_xor(ds, off); num += __shfl_xor(num, off); }
    result = num / (ds + 1e-16f);
  }
  if (lane == 0) logits[wv] = result + bias2[0];
}

// ---------------- layer-3 aggregate (wave per node, 32-wide, 2 edges parallel) ----------------
__global__ __launch_bounds__(256) void agg3_kernel(const float* __restrict__ h3,
    const int* __restrict__ ei, const float* __restrict__ sc,
    const int* __restrict__ row_start, const int* __restrict__ eid,
    const float* __restrict__ bias, float* __restrict__ out, int N) {
  int wv = (blockIdx.x * 256 + threadIdx.x) >> 6;
  int lane = threadIdx.x & 63;
  if (wv >= N) return;
  int start = row_start[wv];
  int deg = row_start[wv + 1] - start;
  int c = lane & 31, par = lane >> 5;
  float acc = 0.f;
  if (deg > 0) {
    int e_l = 0; float s_l = -INFINITY;
    if (lane < deg) { e_l = eid[start + lane]; s_l = sc[e_l]; }
    float m = s_l;
    for (int j = lane + 64; j < deg; j += 64) m = fmaxf(m, sc[eid[start + j]]);
#pragma unroll
    for (int off = 32; off; off >>= 1) m = fmaxf(m, __shfl_xor(m, off));
    float ds = (lane < deg) ? expf(s_l - m) : 0.f;
    for (int j = lane + 64; j < deg; j += 64) ds += expf(sc[eid[start + j]] - m);
#pragma unroll
    for (int off = 32; off; off >>= 1) ds += __shfl_xor(ds, off);
    float inv = 1.0f / (ds + 1e-16f);
    int dmin = deg < 64 ? deg : 64;
    for (int j = par; j < dmin; j += 2) {
      int e = __shfl(e_l, j);
      float w = expf(__shfl(s_l, j) - m) * inv;
      acc += w * h3[(size_t)ei[e] * 32 + c];
    }
    for (int j = 64 + par; j < deg; j += 2) {
      int e = eid[start + j];
      float w = expf(sc[e] - m) * inv;
      acc += w * h3[(size_t)ei[e] * 32 + c];
    }
  }
  acc += __shfl_xor(acc, 32);
  if (par == 0) out[(size_t)wv * 32 + c] = acc + bias[c];
}

// ---------------- node categorical + log_softmax ----------------
__global__ __launch_bounds__(1024) void node_sample_kernel(const float* __restrict__ logits,
    int N, uint32_t ka, uint32_t kb, float* __restrict__ scal) {
  __shared__ float redv[1024];
  __shared__ int redi[1024];
  __shared__ float redm[1024];
  __shared__ float Msh; __shared__ int selsh;
  int tid = threadIdx.x;
  float best = -INFINITY; int bi = 0; float mx = -INFINITY;
  for (int i = tid; i < N; i += 1024) {
    float lg = logits[i];
    mx = fmaxf(mx, lg);
    float v = lg + gumbel_part(ka, kb, (uint32_t)i);
    if (v > best) { best = v; bi = i; }
  }
  redv[tid] = best; redi[tid] = bi; redm[tid] = mx;
  __syncthreads();
  for (int s = 512; s; s >>= 1) {
    if (tid < s) {
      if (redv[tid + s] > redv[tid] ||
          (redv[tid + s] == redv[tid] && redi[tid + s] < redi[tid])) {
        redv[tid] = redv[tid + s]; redi[tid] = redi[tid + s];
      }
      redm[tid] = fmaxf(redm[tid], redm[tid + s]);
    }
    __syncthreads();
  }
  if (tid == 0) { Msh = redm[0]; selsh = redi[0]; }
  __syncthreads();
  float M = Msh;
  float ssum = 0.f;
  for (int i = tid; i < N; i += 1024) ssum += expf(logits[i] - M);
  redv[tid] = ssum;
  __syncthreads();
  for (int s = 512; s; s >>= 1) { if (tid < s) redv[tid] += redv[tid + s]; __syncthreads(); }
  if (tid == 0) {
    int sel = selsh;
    ((int*)scal)[0] = sel;
    scal[1] = M;
    float lS = logf(redv[0]);
    scal[2] = lS;
    scal[3] = logits[sel] - M - lS;
  }
}

// ---------------- action categorical + output ----------------
__global__ __launch_bounds__(64) void action_kernel(const float* __restrict__ out3,
    const float* __restrict__ scal, uint32_t ka, uint32_t kb,
    float* __restrict__ dout, int out_size) {
  int lane = threadIdx.x;
  int sel = ((const int*)scal)[0];
  float v = -INFINITY, noisy = -INFINITY;
  if (lane < 32) {
    v = out3[(size_t)sel * 32 + lane];
    noisy = v + gumbel_part(ka, kb, (uint32_t)lane);
  }
  int idx = lane;
  float nv = noisy;
#pragma unroll
  for (int off = 32; off; off >>= 1) {
    float ov = __shfl_xor(nv, off);
    int oi = __shfl_xor(idx, off);
    if (ov > nv || (ov == nv && oi < idx)) { nv = ov; idx = oi; }
  }
  float vm = v;
#pragma unroll
  for (int off = 32; off; off >>= 1) vm = fmaxf(vm, __shfl_xor(vm, off));
  float ex = (lane < 32) ? expf(v - vm) : 0.f;
#pragma unroll
  for (int off = 32; off; off >>= 1) ex += __shfl_xor(ex, off);
  float vsel = __shfl(v, idx);
  if (lane == 0) {
    float action_lp = vsel - vm - logf(ex);
    dout[0] = (float)sel;
    dout[1] = (float)idx;
    dout[2] = scal[3] + action_lp;
  }
  for (int i = 3 + lane; i < out_size; i += 64) dout[i] = 0.f;
}

extern "C" void kernel_launch(void* const* d_in, const int* in_sizes, int n_in,
                              void* d_out, int out_size, void* d_ws, size_t ws_size,
                              hipStream_t stream) {
  const float* x     = (const float*)d_in[0];
  const int*   ei    = (const int*)d_in[1];
  const float* ea    = (const float*)d_in[2];
  const float* Wl1   = (const float*)d_in[3];
  const float* bl1   = (const float*)d_in[4];
  const float* We1   = (const float*)d_in[5];
  const float* att1  = (const float*)d_in[6];
  const float* bias1 = (const float*)d_in[7];
  const float* Wl2   = (const float*)d_in[8];
  const float* bl2   = (const float*)d_in[9];
  const float* We2   = (const float*)d_in[10];
  const float* att2  = (const float*)d_in[11];
  const float* bias2 = (const float*)d_in[12];
  const float* Wl3   = (const float*)d_in[13];
  const float* bl3   = (const float*)d_in[14];
  const float* We3   = (const float*)d_in[15];
  const float* att3  = (const float*)d_in[16];
  const float* bias3 = (const float*)d_in[17];
  int N = in_sizes[0] / 128;
  int E = in_sizes[1] / 2;
  float* out = (float*)d_out;

  char* p = (char*)d_ws;
  auto alloc = [&](size_t bytes) -> char* {
    char* r = p; p += (bytes + 255) & ~(size_t)255; return r;
  };
  float* h1      = (float*)alloc((size_t)N * 128 * 4);
  float* latent  = (float*)alloc((size_t)N * 128 * 4);
  float* h3      = (float*)alloc((size_t)N * 32 * 4);
  float* h2      = (float*)alloc((size_t)N * 4);
  float* s1      = (float*)alloc((size_t)E * 4);
  float* s2      = (float*)alloc((size_t)E * 4);
  float* s3      = (float*)alloc((size_t)E * 4);
  float* logits  = (float*)alloc((size_t)N * 4);
  float* out3    = (float*)alloc((size_t)N * 32 * 4);
  int* counts    = (int*)alloc((size_t)N * 4);
  int* row_start = (int*)alloc((size_t)(N + 1) * 4);
  int* cursor    = (int*)alloc((size_t)N * 4);
  int* eid       = (int*)alloc((size_t)E * 4);
  float* scal    = (float*)alloc(64);
  (void)ws_size; (void)n_in;

  // JAX PRNG, partitionable semantics (default since JAX 0.4.36):
  // key(42) = (0,42). split via fold-in: subkey_i = TF(key, (0, i)) [both words]
  uint32_t k1a, k1b, k2a, k2b;
  threefry2x32(0u, 42u, 0u, 0u, &k1a, &k1b);
  threefry2x32(0u, 42u, 0u, 1u, &k2a, &k2b);

  hipMemsetAsync(counts, 0, (size_t)N * 4, stream);
  count_kernel<<<(E + 255) / 256, 256, 0, stream>>>(ei, E, counts);
  scan_kernel<<<1, 1024, 0, stream>>>(counts, row_start, cursor, N, E);
  scatter_kernel<<<(E + 255) / 256, 256, 0, stream>>>(ei, E, cursor, eid);

  gemm128_kernel<<<(N + 31) / 32, 256, 0, stream>>>(x, Wl1, bl1, h1, N);
  escore1_kernel<<<(E + 31) / 32, 256, 0, stream>>>(h1, ei, ea, We1, att1, s1, E);
  agg1_kernel<<<(N + 3) / 4, 256, 0, stream>>>(h1, ei, s1, row_start, eid, bias1, latent, N);

  gemm32_kernel<<<((size_t)N * 32 + 255) / 256, 256, 0, stream>>>(latent, Wl3, bl3, h3, N);
  gemv_kernel<<<(N + 3) / 4, 256, 0, stream>>>(latent, Wl2, bl2, h2, N);

  escore2_kernel<<<(E + 255) / 256, 256, 0, stream>>>(h2, ei, ea, We2, att2, s2, E);
  escore3_kernel<<<(E + 63) / 64, 256, 0, stream>>>(h3, ei, ea, We3, att3, s3, E);

  agg2_kernel<<<(N + 3) / 4, 256, 0, stream>>>(h2, ei, s2, row_start, eid, bias2, logits, N);
  agg3_kernel<<<(N + 3) / 4, 256, 0, stream>>>(h3, ei, s3, row_start, eid, bias3, out3, N);

  node_sample_kernel<<<1, 1024, 0, stream>>>(logits, N, k1a, k1b, scal);
  action_kernel<<<1, 64, 0, stream>>>(out3, scal, k2a, k2b, out, out_size);
}

// Round 4
// 794.714 us; speedup vs baseline: 1.1184x; 1.1184x over previous
//
#include <hip/hip_runtime.h>
#include <stdint.h>
#include <math.h>

#define NEG 0.2f
#define TINYF 1.1754943508222875e-38f

// ---------------- Threefry-2x32-20 (matches JAX) ----------------
__host__ __device__ inline void threefry2x32(uint32_t k0, uint32_t k1,
                                             uint32_t x0, uint32_t x1,
                                             uint32_t* o0, uint32_t* o1) {
  uint32_t ks0 = k0, ks1 = k1, ks2 = k0 ^ k1 ^ 0x1BD11BDAu;
  x0 += ks0; x1 += ks1;
#define RR(r) { x0 += x1; x1 = (x1 << (r)) | (x1 >> (32 - (r))); x1 ^= x0; }
  RR(13) RR(15) RR(26) RR(6)
  x0 += ks1; x1 += ks2 + 1u;
  RR(17) RR(29) RR(16) RR(24)
  x0 += ks2; x1 += ks0 + 2u;
  RR(13) RR(15) RR(26) RR(6)
  x0 += ks0; x1 += ks1 + 3u;
  RR(17) RR(29) RR(16) RR(24)
  x0 += ks1; x1 += ks2 + 4u;
  RR(13) RR(15) RR(26) RR(6)
  x0 += ks2; x1 += ks0 + 5u;
#undef RR
  *o0 = x0; *o1 = x1;
}

// jax_threefry_partitionable=True random_bits, bit_width=32:
//   bits[i] = o0 ^ o1 of TF(key, (0, i))   [verified: passes exactly]
__device__ inline float gumbel_part(uint32_t ka, uint32_t kb, uint32_t i) {
  uint32_t o0, o1;
  threefry2x32(ka, kb, 0u, i, &o0, &o1);
  uint32_t bits = o0 ^ o1;
  float f = __uint_as_float((bits >> 9) | 0x3f800000u) - 1.0f;
  float u = fmaxf(TINYF, f + TINYF);
  return -logf(-logf(u));
}

// ---------------- CSR build ----------------
__global__ void count_kernel(const int* __restrict__ ei, int E, int* __restrict__ counts) {
  int e = blockIdx.x * blockDim.x + threadIdx.x;
  if (e < E) atomicAdd(&counts[ei[E + e]], 1);
}

__global__ __launch_bounds__(1024) void scan_kernel(const int* __restrict__ counts,
    int* __restrict__ row_start, int* __restrict__ cursor, int N, int E) {
  __shared__ int a[1024], b[1024];
  __shared__ int base_s;
  int tid = threadIdx.x;
  if (tid == 0) base_s = 0;
  __syncthreads();
  for (int chunk = 0; chunk < N; chunk += 1024) {
    int i = chunk + tid;
    int v = (i < N) ? counts[i] : 0;
    a[tid] = v;
    __syncthreads();
    int* srcp = a; int* dstp = b;
    for (int off = 1; off < 1024; off <<= 1) {
      int val = srcp[tid];
      if (tid >= off) val += srcp[tid - off];
      dstp[tid] = val;
      __syncthreads();
      int* t = srcp; srcp = dstp; dstp = t;
    }
    int incl = srcp[tid];
    int excl = incl - v;
    int base = base_s;
    if (i < N) { row_start[i] = base + excl; cursor[i] = base + excl; }
    __syncthreads();
    if (tid == 1023) base_s = base + incl;
    __syncthreads();
  }
  if (tid == 0) row_start[N] = base_s;
}

__global__ void scatter_kernel(const int* __restrict__ ei, int E,
                               int* __restrict__ cursor, int* __restrict__ eid,
                               int* __restrict__ src_csr) {
  int e = blockIdx.x * blockDim.x + threadIdx.x;
  if (e < E) {
    int d = ei[E + e];
    int p = atomicAdd(&cursor[d], 1);
    eid[p] = e;
    src_csr[p] = ei[e];
  }
}

// ---------------- h = X @ W (128x128) + b ----------------
__global__ __launch_bounds__(256) void gemm128_kernel(const float* __restrict__ X,
    const float* __restrict__ W, const float* __restrict__ bias,
    float* __restrict__ out, int M) {
  __shared__ float xs[128][33];
  int row0 = blockIdx.x * 32;
  int tid = threadIdx.x;
  for (int idx = tid; idx < 32 * 128; idx += 256) {
    int r = idx >> 7;
    int k = idx & 127;
    int row = row0 + r;
    xs[k][r] = (row < M) ? X[(size_t)row * 128 + k] : 0.0f;
  }
  __syncthreads();
  int tc = tid & 31, tr = tid >> 5;
  int c0 = tc * 4, r0 = tr * 4;
  float acc[4][4] = {};
#pragma unroll 4
  for (int k = 0; k < 128; k++) {
    float4 w = *(const float4*)&W[k * 128 + c0];
    float x0 = xs[k][r0], x1 = xs[k][r0 + 1], x2 = xs[k][r0 + 2], x3 = xs[k][r0 + 3];
    acc[0][0] += x0 * w.x; acc[0][1] += x0 * w.y; acc[0][2] += x0 * w.z; acc[0][3] += x0 * w.w;
    acc[1][0] += x1 * w.x; acc[1][1] += x1 * w.y; acc[1][2] += x1 * w.z; acc[1][3] += x1 * w.w;
    acc[2][0] += x2 * w.x; acc[2][1] += x2 * w.y; acc[2][2] += x2 * w.z; acc[2][3] += x2 * w.w;
    acc[3][0] += x3 * w.x; acc[3][1] += x3 * w.y; acc[3][2] += x3 * w.z; acc[3][3] += x3 * w.w;
  }
  float4 b4 = *(const float4*)&bias[c0];
  for (int r = 0; r < 4; r++) {
    int row = row0 + r0 + r;
    if (row < M) {
      float4 o;
      o.x = acc[r][0] + b4.x; o.y = acc[r][1] + b4.y;
      o.z = acc[r][2] + b4.z; o.w = acc[r][3] + b4.w;
      *(float4*)&out[(size_t)row * 128 + c0] = o;
    }
  }
}

// ---------------- h3 = latent @ Wl3 (128x32) + b ----------------
__global__ __launch_bounds__(256) void gemm32_kernel(const float* __restrict__ X,
    const float* __restrict__ W, const float* __restrict__ bias,
    float* __restrict__ out, int M) {
  int t = blockIdx.x * 256 + threadIdx.x;
  int node = t >> 5, c = t & 31;
  if (node >= M) return;
  const float4* xp = (const float4*)&X[(size_t)node * 128];
  float acc = 0.f;
#pragma unroll
  for (int q = 0; q < 32; q++) {
    float4 x4 = xp[q];
    acc += x4.x * W[(q * 4 + 0) * 32 + c] + x4.y * W[(q * 4 + 1) * 32 + c]
         + x4.z * W[(q * 4 + 2) * 32 + c] + x4.w * W[(q * 4 + 3) * 32 + c];
  }
  out[(size_t)node * 32 + c] = acc + bias[c];
}

// ---------------- h2 = latent @ Wl2 (128x1) + b ----------------
__global__ __launch_bounds__(256) void gemv_kernel(const float* __restrict__ X,
    const float* __restrict__ w, const float* __restrict__ b0,
    float* __restrict__ out, int M) {
  int wv = (blockIdx.x * 256 + threadIdx.x) >> 6;
  int lane = threadIdx.x & 63;
  if (wv >= M) return;
  float2 xv = *(const float2*)&X[(size_t)wv * 128 + lane * 2];
  float2 wvv = *(const float2*)&w[lane * 2];
  float v = xv.x * wvv.x + xv.y * wvv.y;
#pragma unroll
  for (int off = 32; off; off >>= 1) v += __shfl_xor(v, off);
  if (lane == 0) out[wv] = v + b0[0];
}

// ---------------- layer-1 fused score+softmax+aggregate (wave per node) ----------------
__global__ __launch_bounds__(256) void fused1_kernel(const float* __restrict__ h,
    const int* __restrict__ src_csr, const int* __restrict__ eid,
    const int* __restrict__ row_start, const float* __restrict__ ea,
    const float* __restrict__ We, const float* __restrict__ att,
    const float* __restrict__ bias, float* __restrict__ out, int N) {
  __shared__ float WeS[2048];
  __shared__ float attS[128];
  int tid = threadIdx.x;
  for (int i = tid; i < 2048; i += 256) WeS[i] = We[i];
  if (tid < 128) attS[tid] = att[tid];
  __syncthreads();
  int wv = (blockIdx.x * 256 + tid) >> 6;
  int lane = tid & 63;
  if (wv >= N) return;
  int l2 = lane * 2;
  float2 attv = *(const float2*)&attS[l2];
  int start = row_start[wv];
  int deg = row_start[wv + 1] - start;
  float2 hi = *(const float2*)&h[(size_t)wv * 128 + l2];
  // preload up to 64 edge ids lane-parallel
  int e_l = 0, s_l = 0;
  if (lane < deg) { e_l = eid[start + lane]; s_l = src_csr[start + lane]; }
  int dcap = deg < 64 ? deg : 64;
  float m = -INFINITY, l = 0.f;
  float2 acc = make_float2(0.f, 0.f);
  for (int j = 0; j < deg; j++) {
    int e, s;
    if (j < dcap) { e = __shfl(e_l, j); s = __shfl(s_l, j); }
    else { e = eid[start + j]; s = src_csr[start + j]; }
    float2 hj = *(const float2*)&h[(size_t)s * 128 + l2];
    const float4* eap = (const float4*)&ea[(size_t)e * 16];
    float v0 = hi.x + hj.x, v1 = hi.y + hj.y;
#pragma unroll
    for (int q = 0; q < 4; q++) {
      float4 a = eap[q];
      float2 w;
      w = *(const float2*)&WeS[(4 * q + 0) * 128 + l2]; v0 += a.x * w.x; v1 += a.x * w.y;
      w = *(const float2*)&WeS[(4 * q + 1) * 128 + l2]; v0 += a.y * w.x; v1 += a.y * w.y;
      w = *(const float2*)&WeS[(4 * q + 2) * 128 + l2]; v0 += a.z * w.x; v1 += a.z * w.y;
      w = *(const float2*)&WeS[(4 * q + 3) * 128 + l2]; v0 += a.w * w.x; v1 += a.w * w.y;
    }
    v0 = v0 >= 0.f ? v0 : NEG * v0;
    v1 = v1 >= 0.f ? v1 : NEG * v1;
    float sc = v0 * attv.x + v1 * attv.y;
#pragma unroll
    for (int off = 32; off; off >>= 1) sc += __shfl_xor(sc, off);
    // online softmax (wave-uniform branch: sc, m identical across lanes)
    if (sc > m) {
      float scale = expf(m - sc);  // exp(-inf)=0 on first edge
      acc.x *= scale; acc.y *= scale; l *= scale;
      m = sc;
    }
    float w = expf(sc - m);
    l += w;
    acc.x += w * hj.x; acc.y += w * hj.y;
  }
  float inv = 1.0f / (l + 1e-16f);
  float2 b2 = *(const float2*)&bias[l2];
  float2 o;
  o.x = acc.x * inv + b2.x;
  o.y = acc.y * inv + b2.y;
  *(float2*)&out[(size_t)wv * 128 + l2] = o;
}

// ---------------- layers 2+3 fused (wave per node, half-wave per edge) ----------------
__global__ __launch_bounds__(256) void fused23_kernel(
    const float* __restrict__ h3, const float* __restrict__ h2,
    const int* __restrict__ src_csr, const int* __restrict__ eid,
    const int* __restrict__ row_start, const float* __restrict__ ea,
    const float* __restrict__ We3, const float* __restrict__ att3,
    const float* __restrict__ bias3, const float* __restrict__ We2,
    const float* __restrict__ att2, const float* __restrict__ bias2,
    float* __restrict__ out3, float* __restrict__ logits, int N) {
  __shared__ float We3S[512];
  __shared__ float att3S[32];
  __shared__ float We2S[16];
  int tid = threadIdx.x;
  for (int i = tid; i < 512; i += 256) We3S[i] = We3[i];
  if (tid < 32) att3S[tid] = att3[tid];
  if (tid < 16) We2S[tid] = We2[tid];
  __syncthreads();
  int wv = (blockIdx.x * 256 + tid) >> 6;
  int lane = tid & 63;
  if (wv >= N) return;
  int c = lane & 31;
  int par = lane >> 5;
  int start = row_start[wv];
  int deg = row_start[wv + 1] - start;
  float bi3 = bias3[c];
  if (deg == 0) {
    if (par == 0) out3[(size_t)wv * 32 + c] = bi3;
    if (lane == 0) logits[wv] = bias2[0];
    return;
  }
  float hi3 = h3[(size_t)wv * 32 + c];
  float hi2 = h2[wv];
  float a2 = att2[0];
  float at3 = att3S[c];
  // preload up to 64 edge ids lane-parallel
  int e_l = 0, s_l = 0;
  if (lane < deg) { e_l = eid[start + lane]; s_l = src_csr[start + lane]; }
  int dcap = deg < 64 ? deg : 64;
  int degUp = (deg + 1) & ~1;
  // per-half-wave online softmax state
  float m3 = -INFINITY, l3 = 0.f, acc3 = 0.f;
  float m2 = -INFINITY, l2 = 0.f, acc2 = 0.f;
  for (int j = par; j < degUp; j += 2) {
    bool act = (j < deg);
    int jj = act ? j : 0;
    int e, s;
    if (jj < dcap) { e = __shfl(e_l, jj); s = __shfl(s_l, jj); }
    else { e = eid[start + jj]; s = src_csr[start + jj]; }
    float hj3 = h3[(size_t)s * 32 + c];
    float h2s = h2[s];
    const float4* eap = (const float4*)&ea[(size_t)e * 16];
    float4 a0 = eap[0], a1 = eap[1], a2v = eap[2], a3v = eap[3];
    // layer-3 score: v3 over 32 dims, reduce within half-wave
    float v3 = hi3 + hj3;
    v3 += a0.x * We3S[0 * 32 + c] + a0.y * We3S[1 * 32 + c] + a0.z * We3S[2 * 32 + c] + a0.w * We3S[3 * 32 + c];
    v3 += a1.x * We3S[4 * 32 + c] + a1.y * We3S[5 * 32 + c] + a1.z * We3S[6 * 32 + c] + a1.w * We3S[7 * 32 + c];
    v3 += a2v.x * We3S[8 * 32 + c] + a2v.y * We3S[9 * 32 + c] + a2v.z * We3S[10 * 32 + c] + a2v.w * We3S[11 * 32 + c];
    v3 += a3v.x * We3S[12 * 32 + c] + a3v.y * We3S[13 * 32 + c] + a3v.z * We3S[14 * 32 + c] + a3v.w * We3S[15 * 32 + c];
    v3 = v3 >= 0.f ? v3 : NEG * v3;
    float t3 = v3 * at3;
#pragma unroll
    for (int off = 16; off; off >>= 1) t3 += __shfl_xor(t3, off);
    // layer-2 score: redundant per-lane compute (no reduce)
    float v2 = hi2 + h2s;
    v2 += a0.x * We2S[0] + a0.y * We2S[1] + a0.z * We2S[2] + a0.w * We2S[3];
    v2 += a1.x * We2S[4] + a1.y * We2S[5] + a1.z * We2S[6] + a1.w * We2S[7];
    v2 += a2v.x * We2S[8] + a2v.y * We2S[9] + a2v.z * We2S[10] + a2v.w * We2S[11];
    v2 += a3v.x * We2S[12] + a3v.y * We2S[13] + a3v.z * We2S[14] + a3v.w * We2S[15];
    v2 = v2 >= 0.f ? v2 : NEG * v2;
    float t2 = v2 * a2;
    if (act) {
      // layer-3 online update
      if (t3 > m3) {
        float sc3 = expf(m3 - t3);
        acc3 *= sc3; l3 *= sc3; m3 = t3;
      }
      float w3 = expf(t3 - m3);
      l3 += w3; acc3 += w3 * hj3;
      // layer-2 online update
      if (t2 > m2) {
        float sc2 = expf(m2 - t2);
        acc2 *= sc2; l2 *= sc2; m2 = t2;
      }
      float w2 = expf(t2 - m2);
      l2 += w2; acc2 += w2 * h2s;
    }
  }
  // merge the two half-wave states (half A always has >=1 edge => M finite)
  float m3o = __shfl_xor(m3, 32), l3o = __shfl_xor(l3, 32), acc3o = __shfl_xor(acc3, 32);
  float M3 = fmaxf(m3, m3o);
  float sA3 = expf(m3 - M3), sB3 = expf(m3o - M3);
  float L3 = l3 * sA3 + l3o * sB3;
  float A3 = acc3 * sA3 + acc3o * sB3;
  float m2o = __shfl_xor(m2, 32), l2o = __shfl_xor(l2, 32), acc2o = __shfl_xor(acc2, 32);
  float M2 = fmaxf(m2, m2o);
  float sA2 = expf(m2 - M2), sB2 = expf(m2o - M2);
  float L2 = l2 * sA2 + l2o * sB2;
  float A2 = acc2 * sA2 + acc2o * sB2;
  if (par == 0) out3[(size_t)wv * 32 + c] = A3 / (L3 + 1e-16f) + bi3;
  if (lane == 0) logits[wv] = A2 / (L2 + 1e-16f) + bias2[0];
}

// ---------------- node categorical + log_softmax ----------------
__global__ __launch_bounds__(1024) void node_sample_kernel(const float* __restrict__ logits,
    int N, uint32_t ka, uint32_t kb, float* __restrict__ scal) {
  __shared__ float redv[1024];
  __shared__ int redi[1024];
  __shared__ float redm[1024];
  __shared__ float Msh; __shared__ int selsh;
  int tid = threadIdx.x;
  float best = -INFINITY; int bi = 0; float mx = -INFINITY;
  for (int i = tid; i < N; i += 1024) {
    float lg = logits[i];
    mx = fmaxf(mx, lg);
    float v = lg + gumbel_part(ka, kb, (uint32_t)i);
    if (v > best) { best = v; bi = i; }
  }
  redv[tid] = best; redi[tid] = bi; redm[tid] = mx;
  __syncthreads();
  for (int s = 512; s; s >>= 1) {
    if (tid < s) {
      if (redv[tid + s] > redv[tid] ||
          (redv[tid + s] == redv[tid] && redi[tid + s] < redi[tid])) {
        redv[tid] = redv[tid + s]; redi[tid] = redi[tid + s];
      }
      redm[tid] = fmaxf(redm[tid], redm[tid + s]);
    }
    __syncthreads();
  }
  if (tid == 0) { Msh = redm[0]; selsh = redi[0]; }
  __syncthreads();
  float M = Msh;
  float ssum = 0.f;
  for (int i = tid; i < N; i += 1024) ssum += expf(logits[i] - M);
  redv[tid] = ssum;
  __syncthreads();
  for (int s = 512; s; s >>= 1) { if (tid < s) redv[tid] += redv[tid + s]; __syncthreads(); }
  if (tid == 0) {
    int sel = selsh;
    ((int*)scal)[0] = sel;
    scal[1] = M;
    float lS = logf(redv[0]);
    scal[2] = lS;
    scal[3] = logits[sel] - M - lS;
  }
}

// ---------------- action categorical + output ----------------
__global__ __launch_bounds__(64) void action_kernel(const float* __restrict__ out3,
    const float* __restrict__ scal, uint32_t ka, uint32_t kb,
    float* __restrict__ dout, int out_size) {
  int lane = threadIdx.x;
  int sel = ((const int*)scal)[0];
  float v = -INFINITY, noisy = -INFINITY;
  if (lane < 32) {
    v = out3[(size_t)sel * 32 + lane];
    noisy = v + gumbel_part(ka, kb, (uint32_t)lane);
  }
  int idx = lane;
  float nv = noisy;
#pragma unroll
  for (int off = 32; off; off >>= 1) {
    float ov = __shfl_xor(nv, off);
    int oi = __shfl_xor(idx, off);
    if (ov > nv || (ov == nv && oi < idx)) { nv = ov; idx = oi; }
  }
  float vm = v;
#pragma unroll
  for (int off = 32; off; off >>= 1) vm = fmaxf(vm, __shfl_xor(vm, off));
  float ex = (lane < 32) ? expf(v - vm) : 0.f;
#pragma unroll
  for (int off = 32; off; off >>= 1) ex += __shfl_xor(ex, off);
  float vsel = __shfl(v, idx);
  if (lane == 0) {
    float action_lp = vsel - vm - logf(ex);
    dout[0] = (float)sel;
    dout[1] = (float)idx;
    dout[2] = scal[3] + action_lp;
  }
  for (int i = 3 + lane; i < out_size; i += 64) dout[i] = 0.f;
}

extern "C" void kernel_launch(void* const* d_in, const int* in_sizes, int n_in,
                              void* d_out, int out_size, void* d_ws, size_t ws_size,
                              hipStream_t stream) {
  const float* x     = (const float*)d_in[0];
  const int*   ei    = (const int*)d_in[1];
  const float* ea    = (const float*)d_in[2];
  const float* Wl1   = (const float*)d_in[3];
  const float* bl1   = (const float*)d_in[4];
  const float* We1   = (const float*)d_in[5];
  const float* att1  = (const float*)d_in[6];
  const float* bias1 = (const float*)d_in[7];
  const float* Wl2   = (const float*)d_in[8];
  const float* bl2   = (const float*)d_in[9];
  const float* We2   = (const float*)d_in[10];
  const float* att2  = (const float*)d_in[11];
  const float* bias2 = (const float*)d_in[12];
  const float* Wl3   = (const float*)d_in[13];
  const float* bl3   = (const float*)d_in[14];
  const float* We3   = (const float*)d_in[15];
  const float* att3  = (const float*)d_in[16];
  const float* bias3 = (const float*)d_in[17];
  int N = in_sizes[0] / 128;
  int E = in_sizes[1] / 2;
  float* out = (float*)d_out;

  char* p = (char*)d_ws;
  auto alloc = [&](size_t bytes) -> char* {
    char* r = p; p += (bytes + 255) & ~(size_t)255; return r;
  };
  float* h1      = (float*)alloc((size_t)N * 128 * 4);
  float* latent  = (float*)alloc((size_t)N * 128 * 4);
  float* h3      = (float*)alloc((size_t)N * 32 * 4);
  float* h2      = (float*)alloc((size_t)N * 4);
  float* logits  = (float*)alloc((size_t)N * 4);
  float* out3    = (float*)alloc((size_t)N * 32 * 4);
  int* counts    = (int*)alloc((size_t)N * 4);
  int* row_start = (int*)alloc((size_t)(N + 1) * 4);
  int* cursor    = (int*)alloc((size_t)N * 4);
  int* eid       = (int*)alloc((size_t)E * 4);
  int* src_csr   = (int*)alloc((size_t)E * 4);
  float* scal    = (float*)alloc(64);
  (void)ws_size; (void)n_in;

  // JAX PRNG (partitionable): key(42)=(0,42); subkey_i = TF(key,(0,i))
  uint32_t k1a, k1b, k2a, k2b;
  threefry2x32(0u, 42u, 0u, 0u, &k1a, &k1b);
  threefry2x32(0u, 42u, 0u, 1u, &k2a, &k2b);

  hipMemsetAsync(counts, 0, (size_t)N * 4, stream);
  count_kernel<<<(E + 255) / 256, 256, 0, stream>>>(ei, E, counts);
  scan_kernel<<<1, 1024, 0, stream>>>(counts, row_start, cursor, N, E);
  scatter_kernel<<<(E + 255) / 256, 256, 0, stream>>>(ei, E, cursor, eid, src_csr);

  gemm128_kernel<<<(N + 31) / 32, 256, 0, stream>>>(x, Wl1, bl1, h1, N);
  fused1_kernel<<<(N + 3) / 4, 256, 0, stream>>>(h1, src_csr, eid, row_start,
                                                 ea, We1, att1, bias1, latent, N);

  gemm32_kernel<<<((size_t)N * 32 + 255) / 256, 256, 0, stream>>>(latent, Wl3, bl3, h3, N);
  gemv_kernel<<<(N + 3) / 4, 256, 0, stream>>>(latent, Wl2, bl2, h2, N);

  fused23_kernel<<<(N + 3) / 4, 256, 0, stream>>>(h3, h2, src_csr, eid, row_start,
                                                  ea, We3, att3, bias3, We2, att2, bias2,
                                                  out3, logits, N);

  node_sample_kernel<<<1, 1024, 0, stream>>>(logits, N, k1a, k1b, scal);
  action_kernel<<<1, 64, 0, stream>>>(out3, scal, k2a, k2b, out, out_size);
}

// Round 5
// 709.956 us; speedup vs baseline: 1.2519x; 1.1194x over previous
//
#include <hip/hip_runtime.h>
#include <stdint.h>
#include <math.h>

#define NEG 0.2f
#define TINYF 1.1754943508222875e-38f

// ---------------- Threefry-2x32-20 (matches JAX) ----------------
__host__ __device__ inline void threefry2x32(uint32_t k0, uint32_t k1,
                                             uint32_t x0, uint32_t x1,
                                             uint32_t* o0, uint32_t* o1) {
  uint32_t ks0 = k0, ks1 = k1, ks2 = k0 ^ k1 ^ 0x1BD11BDAu;
  x0 += ks0; x1 += ks1;
#define RR(r) { x0 += x1; x1 = (x1 << (r)) | (x1 >> (32 - (r))); x1 ^= x0; }
  RR(13) RR(15) RR(26) RR(6)
  x0 += ks1; x1 += ks2 + 1u;
  RR(17) RR(29) RR(16) RR(24)
  x0 += ks2; x1 += ks0 + 2u;
  RR(13) RR(15) RR(26) RR(6)
  x0 += ks0; x1 += ks1 + 3u;
  RR(17) RR(29) RR(16) RR(24)
  x0 += ks1; x1 += ks2 + 4u;
  RR(13) RR(15) RR(26) RR(6)
  x0 += ks2; x1 += ks0 + 5u;
#undef RR
  *o0 = x0; *o1 = x1;
}

// jax_threefry_partitionable=True random_bits, bit_width=32:
//   bits[i] = o0 ^ o1 of TF(key, (0, i))   [verified exact: R3/R4 pass]
__device__ inline float gumbel_part(uint32_t ka, uint32_t kb, uint32_t i) {
  uint32_t o0, o1;
  threefry2x32(ka, kb, 0u, i, &o0, &o1);
  uint32_t bits = o0 ^ o1;
  float f = __uint_as_float((bits >> 9) | 0x3f800000u) - 1.0f;
  float u = fmaxf(TINYF, f + TINYF);
  return -logf(-logf(u));
}

// ---------------- CSR build ----------------
__global__ void count_kernel(const int* __restrict__ ei, int E, int* __restrict__ counts) {
  int e = blockIdx.x * blockDim.x + threadIdx.x;
  if (e < E) atomicAdd(&counts[ei[E + e]], 1);
}

__global__ __launch_bounds__(1024) void scan_kernel(const int* __restrict__ counts,
    int* __restrict__ row_start, int* __restrict__ cursor, int N, int E) {
  __shared__ int a[1024], b[1024];
  __shared__ int base_s;
  int tid = threadIdx.x;
  if (tid == 0) base_s = 0;
  __syncthreads();
  for (int chunk = 0; chunk < N; chunk += 1024) {
    int i = chunk + tid;
    int v = (i < N) ? counts[i] : 0;
    a[tid] = v;
    __syncthreads();
    int* srcp = a; int* dstp = b;
    for (int off = 1; off < 1024; off <<= 1) {
      int val = srcp[tid];
      if (tid >= off) val += srcp[tid - off];
      dstp[tid] = val;
      __syncthreads();
      int* t = srcp; srcp = dstp; dstp = t;
    }
    int incl = srcp[tid];
    int excl = incl - v;
    int base = base_s;
    if (i < N) { row_start[i] = base + excl; cursor[i] = base + excl; }
    __syncthreads();
    if (tid == 1023) base_s = base + incl;
    __syncthreads();
  }
  if (tid == 0) row_start[N] = base_s;
}

__global__ void scatter_kernel(const int* __restrict__ ei, int E,
                               int* __restrict__ cursor, int* __restrict__ eid,
                               int* __restrict__ src_csr) {
  int e = blockIdx.x * blockDim.x + threadIdx.x;
  if (e < E) {
    int d = ei[E + e];
    int p = atomicAdd(&cursor[d], 1);
    eid[p] = e;
    src_csr[p] = ei[e];
  }
}

// ---------------- h = X @ W (128x128) + b ----------------
__global__ __launch_bounds__(256) void gemm128_kernel(const float* __restrict__ X,
    const float* __restrict__ W, const float* __restrict__ bias,
    float* __restrict__ out, int M) {
  __shared__ float xs[128][33];
  int row0 = blockIdx.x * 32;
  int tid = threadIdx.x;
  for (int idx = tid; idx < 32 * 128; idx += 256) {
    int r = idx >> 7;
    int k = idx & 127;
    int row = row0 + r;
    xs[k][r] = (row < M) ? X[(size_t)row * 128 + k] : 0.0f;
  }
  __syncthreads();
  int tc = tid & 31, tr = tid >> 5;
  int c0 = tc * 4, r0 = tr * 4;
  float acc[4][4] = {};
#pragma unroll 4
  for (int k = 0; k < 128; k++) {
    float4 w = *(const float4*)&W[k * 128 + c0];
    float x0 = xs[k][r0], x1 = xs[k][r0 + 1], x2 = xs[k][r0 + 2], x3 = xs[k][r0 + 3];
    acc[0][0] += x0 * w.x; acc[0][1] += x0 * w.y; acc[0][2] += x0 * w.z; acc[0][3] += x0 * w.w;
    acc[1][0] += x1 * w.x; acc[1][1] += x1 * w.y; acc[1][2] += x1 * w.z; acc[1][3] += x1 * w.w;
    acc[2][0] += x2 * w.x; acc[2][1] += x2 * w.y; acc[2][2] += x2 * w.z; acc[2][3] += x2 * w.w;
    acc[3][0] += x3 * w.x; acc[3][1] += x3 * w.y; acc[3][2] += x3 * w.z; acc[3][3] += x3 * w.w;
  }
  float4 b4 = *(const float4*)&bias[c0];
  for (int r = 0; r < 4; r++) {
    int row = row0 + r0 + r;
    if (row < M) {
      float4 o;
      o.x = acc[r][0] + b4.x; o.y = acc[r][1] + b4.y;
      o.z = acc[r][2] + b4.z; o.w = acc[r][3] + b4.w;
      *(float4*)&out[(size_t)row * 128 + c0] = o;
    }
  }
}

// ---------------- h3 = latent @ Wl3 (128x32) + b ----------------
__global__ __launch_bounds__(256) void gemm32_kernel(const float* __restrict__ X,
    const float* __restrict__ W, const float* __restrict__ bias,
    float* __restrict__ out, int M) {
  int t = blockIdx.x * 256 + threadIdx.x;
  int node = t >> 5, c = t & 31;
  if (node >= M) return;
  const float4* xp = (const float4*)&X[(size_t)node * 128];
  float acc = 0.f;
#pragma unroll
  for (int q = 0; q < 32; q++) {
    float4 x4 = xp[q];
    acc += x4.x * W[(q * 4 + 0) * 32 + c] + x4.y * W[(q * 4 + 1) * 32 + c]
         + x4.z * W[(q * 4 + 2) * 32 + c] + x4.w * W[(q * 4 + 3) * 32 + c];
  }
  out[(size_t)node * 32 + c] = acc + bias[c];
}

// ---------------- h2 = latent @ Wl2 (128x1) + b ----------------
__global__ __launch_bounds__(256) void gemv_kernel(const float* __restrict__ X,
    const float* __restrict__ w, const float* __restrict__ b0,
    float* __restrict__ out, int M) {
  int wv = (blockIdx.x * 256 + threadIdx.x) >> 6;
  int lane = threadIdx.x & 63;
  if (wv >= M) return;
  float2 xv = *(const float2*)&X[(size_t)wv * 128 + lane * 2];
  float2 wvv = *(const float2*)&w[lane * 2];
  float v = xv.x * wvv.x + xv.y * wvv.y;
#pragma unroll
  for (int off = 32; off; off >>= 1) v += __shfl_xor(v, off);
  if (lane == 0) out[wv] = v + b0[0];
}

// ---------------- layer-1 fused (wave/node, reg-We, 2-deep pipeline) ----------------
__global__ __launch_bounds__(256) void fused1_kernel(const float* __restrict__ h,
    const int* __restrict__ src_csr, const int* __restrict__ eid,
    const int* __restrict__ row_start, const float* __restrict__ ea,
    const float* __restrict__ We, const float* __restrict__ att,
    const float* __restrict__ bias, float* __restrict__ out, int N) {
  int tid = threadIdx.x;
  int wv = (blockIdx.x * 256 + tid) >> 6;
  int lane = tid & 63;
  if (wv >= N) return;
  int l2 = lane * 2;
  // We column slice in registers: 16 x float2 = 32 VGPRs (no LDS)
  float2 we[16];
#pragma unroll
  for (int k = 0; k < 16; k++) we[k] = *(const float2*)&We[k * 128 + l2];
  float2 attv = *(const float2*)&att[l2];
  float2 b2 = *(const float2*)&bias[l2];
  int start = row_start[wv];
  int deg = row_start[wv + 1] - start;
  if (deg == 0) {
    *(float2*)&out[(size_t)wv * 128 + l2] = b2;
    return;
  }
  float2 hi = *(const float2*)&h[(size_t)wv * 128 + l2];
  int e_l = 0, s_l = 0;
  if (lane < deg) { e_l = eid[start + lane]; s_l = src_csr[start + lane]; }
  int dcap = deg < 64 ? deg : 64;
  // prefetch edge 0
  int e0 = __shfl(e_l, 0), s0 = __shfl(s_l, 0);
  float2 hj = *(const float2*)&h[(size_t)s0 * 128 + l2];
  const float4* eap = (const float4*)&ea[(size_t)e0 * 16];
  float4 a0 = eap[0], a1 = eap[1], a2 = eap[2], a3 = eap[3];
  float m = -INFINITY, l = 0.f;
  float2 acc = make_float2(0.f, 0.f);
  for (int j = 0; j < deg; j++) {
    float2 hjc = hj;
    float4 c0 = a0, c1 = a1, c2 = a2, c3 = a3;
    int jn = j + 1;
    if (jn < deg) {
      int en, sn;
      if (jn < dcap) { en = __shfl(e_l, jn); sn = __shfl(s_l, jn); }
      else { en = eid[start + jn]; sn = src_csr[start + jn]; }
      hj = *(const float2*)&h[(size_t)sn * 128 + l2];
      const float4* eapn = (const float4*)&ea[(size_t)en * 16];
      a0 = eapn[0]; a1 = eapn[1]; a2 = eapn[2]; a3 = eapn[3];
    }
    float v0 = hi.x + hjc.x, v1 = hi.y + hjc.y;
    v0 += c0.x * we[0].x;  v1 += c0.x * we[0].y;
    v0 += c0.y * we[1].x;  v1 += c0.y * we[1].y;
    v0 += c0.z * we[2].x;  v1 += c0.z * we[2].y;
    v0 += c0.w * we[3].x;  v1 += c0.w * we[3].y;
    v0 += c1.x * we[4].x;  v1 += c1.x * we[4].y;
    v0 += c1.y * we[5].x;  v1 += c1.y * we[5].y;
    v0 += c1.z * we[6].x;  v1 += c1.z * we[6].y;
    v0 += c1.w * we[7].x;  v1 += c1.w * we[7].y;
    v0 += c2.x * we[8].x;  v1 += c2.x * we[8].y;
    v0 += c2.y * we[9].x;  v1 += c2.y * we[9].y;
    v0 += c2.z * we[10].x; v1 += c2.z * we[10].y;
    v0 += c2.w * we[11].x; v1 += c2.w * we[11].y;
    v0 += c3.x * we[12].x; v1 += c3.x * we[12].y;
    v0 += c3.y * we[13].x; v1 += c3.y * we[13].y;
    v0 += c3.z * we[14].x; v1 += c3.z * we[14].y;
    v0 += c3.w * we[15].x; v1 += c3.w * we[15].y;
    v0 = v0 >= 0.f ? v0 : NEG * v0;
    v1 = v1 >= 0.f ? v1 : NEG * v1;
    float sc = v0 * attv.x + v1 * attv.y;
#pragma unroll
    for (int off = 32; off; off >>= 1) sc += __shfl_xor(sc, off);
    // branchless online softmax (sc wave-uniform)
    float mn = fmaxf(m, sc);
    float scale = __expf(m - mn);   // first iter: exp(-inf)=0
    float w = __expf(sc - mn);
    l = l * scale + w;
    acc.x = acc.x * scale + w * hjc.x;
    acc.y = acc.y * scale + w * hjc.y;
    m = mn;
  }
  float inv = 1.0f / (l + 1e-16f);
  float2 o;
  o.x = acc.x * inv + b2.x;
  o.y = acc.y * inv + b2.y;
  *(float2*)&out[(size_t)wv * 128 + l2] = o;
}

// ---------------- layers 2+3 fused (wave/node, half-wave/edge, reg-We, pipelined) ----------------
__global__ __launch_bounds__(256) void fused23_kernel(
    const float* __restrict__ h3, const float* __restrict__ h2,
    const int* __restrict__ src_csr, const int* __restrict__ eid,
    const int* __restrict__ row_start, const float* __restrict__ ea,
    const float* __restrict__ We3, const float* __restrict__ att3,
    const float* __restrict__ bias3, const float* __restrict__ We2,
    const float* __restrict__ att2, const float* __restrict__ bias2,
    float* __restrict__ out3, float* __restrict__ logits, int N) {
  int tid = threadIdx.x;
  int wv = (blockIdx.x * 256 + tid) >> 6;
  int lane = tid & 63;
  if (wv >= N) return;
  int c = lane & 31;
  int par = lane >> 5;
  // register weights: We3 column (16), We2 (uniform -> SGPR), att
  float we3[16];
#pragma unroll
  for (int k = 0; k < 16; k++) we3[k] = We3[k * 32 + c];
  float we2[16];
#pragma unroll
  for (int k = 0; k < 16; k++) we2[k] = We2[k];
  float at3 = att3[c];
  float a2s = att2[0];
  float bi3 = bias3[c];
  int start = row_start[wv];
  int deg = row_start[wv + 1] - start;
  if (deg == 0) {
    if (par == 0) out3[(size_t)wv * 32 + c] = bi3;
    if (lane == 0) logits[wv] = bias2[0];
    return;
  }
  float hi3 = h3[(size_t)wv * 32 + c];
  float hi2 = h2[wv];
  int e_l = 0, s_l = 0;
  if (lane < deg) { e_l = eid[start + lane]; s_l = src_csr[start + lane]; }
  int dcap = deg < 64 ? deg : 64;
  int degUp = (deg + 1) & ~1;
  // prefetch first edge for this half-wave (j = par)
  {
  }
  int jj0 = (par < deg) ? par : 0;
  int e0, s0;
  if (jj0 < dcap) { e0 = __shfl(e_l, jj0); s0 = __shfl(s_l, jj0); }
  else { e0 = eid[start + jj0]; s0 = src_csr[start + jj0]; }
  float nhj3 = h3[(size_t)s0 * 32 + c];
  float nh2s = h2[s0];
  const float4* eap0 = (const float4*)&ea[(size_t)e0 * 16];
  float4 na0 = eap0[0], na1 = eap0[1], na2 = eap0[2], na3 = eap0[3];
  float m3 = -INFINITY, l3 = 0.f, acc3 = 0.f;
  float m2 = -INFINITY, l2 = 0.f, acc2 = 0.f;
  for (int j = par; j < degUp; j += 2) {
    float hj3 = nhj3, h2s = nh2s;
    float4 c0 = na0, c1 = na1, c2 = na2, c3 = na3;
    int jn = j + 2;
    if (jn < degUp) {
      int jjn = (jn < deg) ? jn : 0;
      int en, sn;
      if (jjn < dcap) { en = __shfl(e_l, jjn); sn = __shfl(s_l, jjn); }
      else { en = eid[start + jjn]; sn = src_csr[start + jjn]; }
      nhj3 = h3[(size_t)sn * 32 + c];
      nh2s = h2[sn];
      const float4* eapn = (const float4*)&ea[(size_t)en * 16];
      na0 = eapn[0]; na1 = eapn[1]; na2 = eapn[2]; na3 = eapn[3];
    }
    // layer-3 score (32 dims across half-wave)
    float v3 = hi3 + hj3;
    v3 += c0.x * we3[0]  + c0.y * we3[1]  + c0.z * we3[2]  + c0.w * we3[3];
    v3 += c1.x * we3[4]  + c1.y * we3[5]  + c1.z * we3[6]  + c1.w * we3[7];
    v3 += c2.x * we3[8]  + c2.y * we3[9]  + c2.z * we3[10] + c2.w * we3[11];
    v3 += c3.x * we3[12] + c3.y * we3[13] + c3.z * we3[14] + c3.w * we3[15];
    v3 = v3 >= 0.f ? v3 : NEG * v3;
    float t3 = v3 * at3;
#pragma unroll
    for (int off = 16; off; off >>= 1) t3 += __shfl_xor(t3, off);
    // layer-2 score (redundant per-lane)
    float v2 = hi2 + h2s;
    v2 += c0.x * we2[0]  + c0.y * we2[1]  + c0.z * we2[2]  + c0.w * we2[3];
    v2 += c1.x * we2[4]  + c1.y * we2[5]  + c1.z * we2[6]  + c1.w * we2[7];
    v2 += c2.x * we2[8]  + c2.y * we2[9]  + c2.z * we2[10] + c2.w * we2[11];
    v2 += c3.x * we2[12] + c3.y * we2[13] + c3.z * we2[14] + c3.w * we2[15];
    v2 = v2 >= 0.f ? v2 : NEG * v2;
    float t2 = v2 * a2s;
    if (j < deg) {
      float mn3 = fmaxf(m3, t3);
      float sc3 = __expf(m3 - mn3);
      float w3 = __expf(t3 - mn3);
      l3 = l3 * sc3 + w3;
      acc3 = acc3 * sc3 + w3 * hj3;
      m3 = mn3;
      float mn2 = fmaxf(m2, t2);
      float sc2 = __expf(m2 - mn2);
      float w2 = __expf(t2 - mn2);
      l2 = l2 * sc2 + w2;
      acc2 = acc2 * sc2 + w2 * h2s;
      m2 = mn2;
    }
  }
  // merge two half-wave states (half A has >=1 edge => finite after merge)
  float m3o = __shfl_xor(m3, 32), l3o = __shfl_xor(l3, 32), acc3o = __shfl_xor(acc3, 32);
  float M3 = fmaxf(m3, m3o);
  float sA3 = (m3 == -INFINITY) ? 0.f : __expf(m3 - M3);
  float sB3 = (m3o == -INFINITY) ? 0.f : __expf(m3o - M3);
  float L3 = l3 * sA3 + l3o * sB3;
  float A3 = acc3 * sA3 + acc3o * sB3;
  float m2o = __shfl_xor(m2, 32), l2o = __shfl_xor(l2, 32), acc2o = __shfl_xor(acc2, 32);
  float M2 = fmaxf(m2, m2o);
  float sA2 = (m2 == -INFINITY) ? 0.f : __expf(m2 - M2);
  float sB2 = (m2o == -INFINITY) ? 0.f : __expf(m2o - M2);
  float L2 = l2 * sA2 + l2o * sB2;
  float A2 = acc2 * sA2 + acc2o * sB2;
  if (par == 0) out3[(size_t)wv * 32 + c] = A3 / (L3 + 1e-16f) + bi3;
  if (lane == 0) logits[wv] = A2 / (L2 + 1e-16f) + bias2[0];
}

// ---------------- node categorical: 64-block partial + 1-wave final ----------------
#define NSB 64
__global__ __launch_bounds__(256) void node_partial_kernel(const float* __restrict__ logits,
    int N, uint32_t ka, uint32_t kb,
    float* __restrict__ pB, int* __restrict__ pI,
    float* __restrict__ pM, float* __restrict__ pL) {
  int chunk = (N + NSB - 1) / NSB;
  int s0 = blockIdx.x * chunk;
  int s1 = s0 + chunk; if (s1 > N) s1 = N;
  int tid = threadIdx.x;
  float best = -INFINITY; int bi = 0x7fffffff;
  float m = -INFINITY, l = 0.f;
  for (int i = s0 + tid; i < s1; i += 256) {
    float lg = logits[i];
    float mn = fmaxf(m, lg);
    l = l * __expf(m - mn) + __expf(lg - mn);
    m = mn;
    float v = lg + gumbel_part(ka, kb, (uint32_t)i);
    if (v > best) { best = v; bi = i; }
  }
  __shared__ float sb[256], sm[256], sl[256];
  __shared__ int si[256];
  sb[tid] = best; si[tid] = bi; sm[tid] = m; sl[tid] = l;
  __syncthreads();
  for (int s = 128; s; s >>= 1) {
    if (tid < s) {
      if (sb[tid + s] > sb[tid] || (sb[tid + s] == sb[tid] && si[tid + s] < si[tid])) {
        sb[tid] = sb[tid + s]; si[tid] = si[tid + s];
      }
      float M = fmaxf(sm[tid], sm[tid + s]);
      float t0 = (sm[tid] == -INFINITY) ? 0.f : sl[tid] * __expf(sm[tid] - M);
      float t1 = (sm[tid + s] == -INFINITY) ? 0.f : sl[tid + s] * __expf(sm[tid + s] - M);
      sm[tid] = M; sl[tid] = t0 + t1;
    }
    __syncthreads();
  }
  if (tid == 0) { pB[blockIdx.x] = sb[0]; pI[blockIdx.x] = si[0]; pM[blockIdx.x] = sm[0]; pL[blockIdx.x] = sl[0]; }
}

__global__ __launch_bounds__(64) void node_final_kernel(const float* __restrict__ logits,
    const float* __restrict__ pB, const int* __restrict__ pI,
    const float* __restrict__ pM, const float* __restrict__ pL,
    float* __restrict__ scal) {
  int lane = threadIdx.x;
  float best = pB[lane]; int bi = pI[lane];
  float m = pM[lane]; float l = pL[lane];
#pragma unroll
  for (int off = 32; off; off >>= 1) {
    float ob = __shfl_xor(best, off); int oi = __shfl_xor(bi, off);
    if (ob > best || (ob == best && oi < bi)) { best = ob; bi = oi; }
    float om = __shfl_xor(m, off); float ol = __shfl_xor(l, off);
    float M = fmaxf(m, om);
    float t0 = (m == -INFINITY) ? 0.f : l * __expf(m - M);
    float t1 = (om == -INFINITY) ? 0.f : ol * __expf(om - M);
    m = M; l = t0 + t1;
  }
  if (lane == 0) {
    ((int*)scal)[0] = bi;
    scal[3] = logits[bi] - (m + logf(l));
  }
}

// ---------------- action categorical + output ----------------
__global__ __launch_bounds__(64) void action_kernel(const float* __restrict__ out3,
    const float* __restrict__ scal, uint32_t ka, uint32_t kb,
    float* __restrict__ dout, int out_size) {
  int lane = threadIdx.x;
  int sel = ((const int*)scal)[0];
  float v = -INFINITY, noisy = -INFINITY;
  if (lane < 32) {
    v = out3[(size_t)sel * 32 + lane];
    noisy = v + gumbel_part(ka, kb, (uint32_t)lane);
  }
  int idx = lane;
  float nv = noisy;
#pragma unroll
  for (int off = 32; off; off >>= 1) {
    float ov = __shfl_xor(nv, off);
    int oi = __shfl_xor(idx, off);
    if (ov > nv || (ov == nv && oi < idx)) { nv = ov; idx = oi; }
  }
  float vm = v;
#pragma unroll
  for (int off = 32; off; off >>= 1) vm = fmaxf(vm, __shfl_xor(vm, off));
  float ex = (lane < 32) ? expf(v - vm) : 0.f;
#pragma unroll
  for (int off = 32; off; off >>= 1) ex += __shfl_xor(ex, off);
  float vsel = __shfl(v, idx);
  if (lane == 0) {
    float action_lp = vsel - vm - logf(ex);
    dout[0] = (float)sel;
    dout[1] = (float)idx;
    dout[2] = scal[3] + action_lp;
  }
  for (int i = 3 + lane; i < out_size; i += 64) dout[i] = 0.f;
}

extern "C" void kernel_launch(void* const* d_in, const int* in_sizes, int n_in,
                              void* d_out, int out_size, void* d_ws, size_t ws_size,
                              hipStream_t stream) {
  const float* x     = (const float*)d_in[0];
  const int*   ei    = (const int*)d_in[1];
  const float* ea    = (const float*)d_in[2];
  const float* Wl1   = (const float*)d_in[3];
  const float* bl1   = (const float*)d_in[4];
  const float* We1   = (const float*)d_in[5];
  const float* att1  = (const float*)d_in[6];
  const float* bias1 = (const float*)d_in[7];
  const float* Wl2   = (const float*)d_in[8];
  const float* bl2   = (const float*)d_in[9];
  const float* We2   = (const float*)d_in[10];
  const float* att2  = (const float*)d_in[11];
  const float* bias2 = (const float*)d_in[12];
  const float* Wl3   = (const float*)d_in[13];
  const float* bl3   = (const float*)d_in[14];
  const float* We3   = (const float*)d_in[15];
  const float* att3  = (const float*)d_in[16];
  const float* bias3 = (const float*)d_in[17];
  int N = in_sizes[0] / 128;
  int E = in_sizes[1] / 2;
  float* out = (float*)d_out;

  char* p = (char*)d_ws;
  auto alloc = [&](size_t bytes) -> char* {
    char* r = p; p += (bytes + 255) & ~(size_t)255; return r;
  };
  float* h1      = (float*)alloc((size_t)N * 128 * 4);
  float* latent  = (float*)alloc((size_t)N * 128 * 4);
  float* h3      = (float*)alloc((size_t)N * 32 * 4);
  float* h2      = (float*)alloc((size_t)N * 4);
  float* logits  = (float*)alloc((size_t)N * 4);
  float* out3    = (float*)alloc((size_t)N * 32 * 4);
  int* counts    = (int*)alloc((size_t)N * 4);
  int* row_start = (int*)alloc((size_t)(N + 1) * 4);
  int* cursor    = (int*)alloc((size_t)N * 4);
  int* eid       = (int*)alloc((size_t)E * 4);
  int* src_csr   = (int*)alloc((size_t)E * 4);
  float* pB      = (float*)alloc(NSB * 4);
  int*   pI      = (int*)alloc(NSB * 4);
  float* pM      = (float*)alloc(NSB * 4);
  float* pL      = (float*)alloc(NSB * 4);
  float* scal    = (float*)alloc(64);
  (void)ws_size; (void)n_in;

  // JAX PRNG (partitionable): key(42)=(0,42); subkey_i = TF(key,(0,i))
  uint32_t k1a, k1b, k2a, k2b;
  threefry2x32(0u, 42u, 0u, 0u, &k1a, &k1b);
  threefry2x32(0u, 42u, 0u, 1u, &k2a, &k2b);

  hipMemsetAsync(counts, 0, (size_t)N * 4, stream);
  count_kernel<<<(E + 255) / 256, 256, 0, stream>>>(ei, E, counts);
  scan_kernel<<<1, 1024, 0, stream>>>(counts, row_start, cursor, N, E);
  scatter_kernel<<<(E + 255) / 256, 256, 0, stream>>>(ei, E, cursor, eid, src_csr);

  gemm128_kernel<<<(N + 31) / 32, 256, 0, stream>>>(x, Wl1, bl1, h1, N);
  fused1_kernel<<<(N + 3) / 4, 256, 0, stream>>>(h1, src_csr, eid, row_start,
                                                 ea, We1, att1, bias1, latent, N);

  gemm32_kernel<<<((size_t)N * 32 + 255) / 256, 256, 0, stream>>>(latent, Wl3, bl3, h3, N);
  gemv_kernel<<<(N + 3) / 4, 256, 0, stream>>>(latent, Wl2, bl2, h2, N);

  fused23_kernel<<<(N + 3) / 4, 256, 0, stream>>>(h3, h2, src_csr, eid, row_start,
                                                  ea, We3, att3, bias3, We2, att2, bias2,
                                                  out3, logits, N);

  node_partial_kernel<<<NSB, 256, 0, stream>>>(logits, N, k1a, k1b, pB, pI, pM, pL);
  node_final_kernel<<<1, 64, 0, stream>>>(logits, pB, pI, pM, pL, scal);
  action_kernel<<<1, 64, 0, stream>>>(out3, scal, k2a, k2b, out, out_size);
}